// Round 2
// baseline (679.426 us; speedup 1.0000x reference)
//
#include <hip/hip_runtime.h>
#include <hip/hip_bf16.h>
#include <math.h>

// Problem: B=256, S=196, D=2048, H=512
//   att_h  = h @ W_h2att^T + b_h2att              [B,H]
//   scores = sum_h tanh(p_att + att_h) * w_alpha  [B,S]
//   weight = renorm(softmax(scores) * mask)       [B,S]
//   out    = sum_s weight * att_feats             [B,D]

#define B_ 256
#define S_ 196
#define D_ 2048
#define H_ 512

// fast tanh: 1 - 2/(exp(2x)+1). exp via v_exp_f32, rcp via v_rcp_f32.
// abs err ~1e-6, saturates correctly at +/-1 for large |x|.
__device__ __forceinline__ float fast_tanh(float x) {
  float e = __expf(2.0f * x);
  return 1.0f - 2.0f * __builtin_amdgcn_rcpf(e + 1.0f);
}

// ---------------------------------------------------------------------------
// Kernel 1: att_h[b,j] = sum_d h[b,d] * W[j,d] + bias[j]
// NT GEMM, M=256, N=512, K=2048. 32x32 tiles, BK=32, 256 threads, 2x2/thread.
// ---------------------------------------------------------------------------
__global__ __launch_bounds__(256) void h2att_kernel(
    const float* __restrict__ h, const float* __restrict__ W,
    const float* __restrict__ bias, float* __restrict__ att_h) {
  __shared__ float lds_a[32][33];
  __shared__ float lds_b[32][33];

  const int tid = threadIdx.x;
  const int m0 = blockIdx.y * 32;   // over B
  const int n0 = blockIdx.x * 32;   // over H

  const int lr = tid >> 3;          // 0..31 row for loading
  const int lc = (tid & 7) * 4;     // 0..28 col4 for loading
  const int tm = tid >> 4;          // 0..15
  const int tn = tid & 15;          // 0..15

  float acc00 = 0.f, acc01 = 0.f, acc10 = 0.f, acc11 = 0.f;

  for (int k0 = 0; k0 < D_; k0 += 32) {
    float4 av = *(const float4*)(h + (size_t)(m0 + lr) * D_ + k0 + lc);
    float4 bv = *(const float4*)(W + (size_t)(n0 + lr) * D_ + k0 + lc);
    __syncthreads();
    lds_a[lr][lc + 0] = av.x; lds_a[lr][lc + 1] = av.y;
    lds_a[lr][lc + 2] = av.z; lds_a[lr][lc + 3] = av.w;
    lds_b[lr][lc + 0] = bv.x; lds_b[lr][lc + 1] = bv.y;
    lds_b[lr][lc + 2] = bv.z; lds_b[lr][lc + 3] = bv.w;
    __syncthreads();
#pragma unroll
    for (int kk = 0; kk < 32; ++kk) {
      float a0 = lds_a[tm][kk];
      float a1 = lds_a[tm + 16][kk];
      float b0 = lds_b[tn][kk];
      float b1 = lds_b[tn + 16][kk];
      acc00 = fmaf(a0, b0, acc00);
      acc01 = fmaf(a0, b1, acc01);
      acc10 = fmaf(a1, b0, acc10);
      acc11 = fmaf(a1, b1, acc11);
    }
  }

  const int m = m0 + tm, n = n0 + tn;
  float bn0 = bias[n], bn1 = bias[n + 16];
  att_h[(size_t)m * H_ + n]              = acc00 + bn0;
  att_h[(size_t)m * H_ + n + 16]         = acc01 + bn1;
  att_h[(size_t)(m + 16) * H_ + n]       = acc10 + bn0;
  att_h[(size_t)(m + 16) * H_ + n + 16]  = acc11 + bn1;
}

// ---------------------------------------------------------------------------
// Kernel 2: scores[b,s] = sum_h tanh(p[b,s,h] + att_h[b,h]) * w_alpha[h] + b_a
// One wave (64 lanes) per (b,s). 4 waves / block. Streams 103 MB of p.
// ---------------------------------------------------------------------------
__global__ __launch_bounds__(256) void scores_kernel(
    const float* __restrict__ p, const float* __restrict__ att_h,
    const float* __restrict__ w_alpha, const float* __restrict__ b_alpha,
    float* __restrict__ scores) {
  const int wave = threadIdx.x >> 6;
  const int lane = threadIdx.x & 63;
  const int idx = blockIdx.x * 4 + wave;   // 0 .. B*S-1  (12544*4 = 50176 exact)
  const int b = idx / S_;

  const float* pp = p + (size_t)idx * H_;
  const float* ah = att_h + (size_t)b * H_;

  float acc = 0.f;
#pragma unroll
  for (int h0 = 0; h0 < H_; h0 += 256) {
    const int o = h0 + lane * 4;
    float4 pv = *(const float4*)(pp + o);
    float4 av = *(const float4*)(ah + o);
    float4 wv = *(const float4*)(w_alpha + o);
    acc += fast_tanh(pv.x + av.x) * wv.x;
    acc += fast_tanh(pv.y + av.y) * wv.y;
    acc += fast_tanh(pv.z + av.z) * wv.z;
    acc += fast_tanh(pv.w + av.w) * wv.w;
  }
#pragma unroll
  for (int off = 32; off > 0; off >>= 1) acc += __shfl_down(acc, off);
  if (lane == 0) scores[idx] = acc + b_alpha[0];
}

// ---------------------------------------------------------------------------
// Kernel 3: weight[b,s] = renorm(softmax(scores[b,:]) * mask[b,:]).
// One block of 256 threads per b (threads 196..255 padded). Tiny kernel.
// ---------------------------------------------------------------------------
__global__ __launch_bounds__(256) void softmax_kernel(
    const float* __restrict__ scores, const float* __restrict__ mask,
    float* __restrict__ weight) {
  __shared__ float red[4];
  const int tid = threadIdx.x;
  const int b = blockIdx.x;
  const int wave = tid >> 6, lane = tid & 63;

  float sc = (tid < S_) ? scores[(size_t)b * S_ + tid] : -INFINITY;

  float v = sc;
#pragma unroll
  for (int off = 32; off > 0; off >>= 1) v = fmaxf(v, __shfl_down(v, off));
  if (lane == 0) red[wave] = v;
  __syncthreads();
  float mx = fmaxf(fmaxf(red[0], red[1]), fmaxf(red[2], red[3]));
  __syncthreads();

  float e = (tid < S_) ? __expf(sc - mx) : 0.f;

  v = e;
#pragma unroll
  for (int off = 32; off > 0; off >>= 1) v += __shfl_down(v, off);
  if (lane == 0) red[wave] = v;
  __syncthreads();
  float z = red[0] + red[1] + red[2] + red[3];
  __syncthreads();

  float w = (tid < S_) ? (e / z) * mask[(size_t)b * S_ + tid] : 0.f;

  v = w;
#pragma unroll
  for (int off = 32; off > 0; off >>= 1) v += __shfl_down(v, off);
  if (lane == 0) red[wave] = v;
  __syncthreads();
  float z2 = red[0] + red[1] + red[2] + red[3];

  if (tid < S_) weight[(size_t)b * S_ + tid] = w / z2;
}

// ---------------------------------------------------------------------------
// Kernel 4: out[b,d] = sum_s weight[b,s] * att_feats[b,s,d].
// grid = (D/512, B) = (4, 256) = 1024 blocks, 128 threads, float4/thread.
// s-loop unrolled x7 -> 7 float4 loads in flight per thread (7 KB/wave).
// ---------------------------------------------------------------------------
__global__ __launch_bounds__(128) void attres_kernel(
    const float* __restrict__ weight, const float* __restrict__ att_feats,
    float* __restrict__ out) {
  __shared__ float w_lds[S_];
  const int tid = threadIdx.x;
  const int b = blockIdx.y;

  if (tid < S_) w_lds[tid] = weight[(size_t)b * S_ + tid];
  if (tid + 128 < S_) w_lds[tid + 128] = weight[(size_t)b * S_ + tid + 128];
  __syncthreads();

  const int d0 = blockIdx.x * 512 + tid * 4;
  const float* base = att_feats + (size_t)b * S_ * D_ + d0;

  float4 acc = {0.f, 0.f, 0.f, 0.f};
#pragma unroll 2
  for (int so = 0; so < S_; so += 7) {      // 196 = 28 * 7
    float4 v0 = *(const float4*)(base + (size_t)(so + 0) * D_);
    float4 v1 = *(const float4*)(base + (size_t)(so + 1) * D_);
    float4 v2 = *(const float4*)(base + (size_t)(so + 2) * D_);
    float4 v3 = *(const float4*)(base + (size_t)(so + 3) * D_);
    float4 v4 = *(const float4*)(base + (size_t)(so + 4) * D_);
    float4 v5 = *(const float4*)(base + (size_t)(so + 5) * D_);
    float4 v6 = *(const float4*)(base + (size_t)(so + 6) * D_);
    float w0 = w_lds[so + 0], w1 = w_lds[so + 1], w2 = w_lds[so + 2];
    float w3 = w_lds[so + 3], w4 = w_lds[so + 4], w5 = w_lds[so + 5];
    float w6 = w_lds[so + 6];
    acc.x = fmaf(w0, v0.x, acc.x); acc.y = fmaf(w0, v0.y, acc.y);
    acc.z = fmaf(w0, v0.z, acc.z); acc.w = fmaf(w0, v0.w, acc.w);
    acc.x = fmaf(w1, v1.x, acc.x); acc.y = fmaf(w1, v1.y, acc.y);
    acc.z = fmaf(w1, v1.z, acc.z); acc.w = fmaf(w1, v1.w, acc.w);
    acc.x = fmaf(w2, v2.x, acc.x); acc.y = fmaf(w2, v2.y, acc.y);
    acc.z = fmaf(w2, v2.z, acc.z); acc.w = fmaf(w2, v2.w, acc.w);
    acc.x = fmaf(w3, v3.x, acc.x); acc.y = fmaf(w3, v3.y, acc.y);
    acc.z = fmaf(w3, v3.z, acc.z); acc.w = fmaf(w3, v3.w, acc.w);
    acc.x = fmaf(w4, v4.x, acc.x); acc.y = fmaf(w4, v4.y, acc.y);
    acc.z = fmaf(w4, v4.z, acc.z); acc.w = fmaf(w4, v4.w, acc.w);
    acc.x = fmaf(w5, v5.x, acc.x); acc.y = fmaf(w5, v5.y, acc.y);
    acc.z = fmaf(w5, v5.z, acc.z); acc.w = fmaf(w5, v5.w, acc.w);
    acc.x = fmaf(w6, v6.x, acc.x); acc.y = fmaf(w6, v6.y, acc.y);
    acc.z = fmaf(w6, v6.z, acc.z); acc.w = fmaf(w6, v6.w, acc.w);
  }
  *(float4*)(out + (size_t)b * D_ + d0) = acc;
}

// ---------------------------------------------------------------------------
extern "C" void kernel_launch(void* const* d_in, const int* in_sizes, int n_in,
                              void* d_out, int out_size, void* d_ws, size_t ws_size,
                              hipStream_t stream) {
  const float* h         = (const float*)d_in[0];   // [B,D]
  const float* att_feats = (const float*)d_in[1];   // [B,S,D]
  const float* p_att     = (const float*)d_in[2];   // [B,S,H]
  const float* att_masks = (const float*)d_in[3];   // [B,S]
  const float* W_h2att   = (const float*)d_in[4];   // [H,D]
  const float* b_h2att   = (const float*)d_in[5];   // [H]
  const float* w_alpha   = (const float*)d_in[6];   // [H]
  const float* b_alpha   = (const float*)d_in[7];   // [1]
  float* out = (float*)d_out;                       // [B,D]

  float* att_h  = (float*)d_ws;                     // B*H = 131072 floats
  float* scores = att_h + (size_t)B_ * H_;          // B*S = 50176 floats
  float* weight = scores + (size_t)B_ * S_;         // B*S = 50176 floats

  // K1: att_h  (128 blocks)
  dim3 g1(H_ / 32, B_ / 32);
  h2att_kernel<<<g1, 256, 0, stream>>>(h, W_h2att, b_h2att, att_h);

  // K2: scores (12544 blocks, streams p_att 103 MB)
  scores_kernel<<<(B_ * S_) / 4, 256, 0, stream>>>(p_att, att_h, w_alpha,
                                                   b_alpha, scores);

  // K3: softmax -> weight (256 blocks, tiny)
  softmax_kernel<<<B_, 256, 0, stream>>>(scores, att_masks, weight);

  // K4: weighted sum (1024 blocks, streams att_feats 411 MB)
  dim3 g4(D_ / 512, B_);
  attres_kernel<<<g4, 128, 0, stream>>>(weight, att_feats, out);
}

// Round 3
// 638.426 us; speedup vs baseline: 1.0642x; 1.0642x over previous
//
#include <hip/hip_runtime.h>
#include <hip/hip_bf16.h>
#include <math.h>

// Problem: B=256, S=196, D=2048, H=512
//   att_h  = h @ W_h2att^T + b_h2att              [B,H]
//   scores = sum_h tanh(p_att + att_h) * w_alpha  [B,S]
//   weight = renorm(softmax(scores) * mask)       [B,S]
//   out    = sum_s weight * att_feats             [B,D]

#define B_ 256
#define S_ 196
#define D_ 2048
#define H_ 512

// fast tanh: 1 - 2/(exp(2x)+1). abs err ~1e-6, saturates at +/-1.
__device__ __forceinline__ float fast_tanh(float x) {
  float e = __expf(2.0f * x);
  return 1.0f - 2.0f * __builtin_amdgcn_rcpf(e + 1.0f);
}

// ---------------------------------------------------------------------------
// Kernel 0: att_h[m,n] = bias[n]  (init target for split-K atomics)
// 131072 floats; grid 128 x 256 threads, float4 per thread.
// ---------------------------------------------------------------------------
__global__ __launch_bounds__(256) void bias_init_kernel(
    const float* __restrict__ bias, float* __restrict__ att_h) {
  const int idx = blockIdx.x * 256 + threadIdx.x;       // 0..32767
  const int n4 = (idx * 4) & (H_ - 1);                  // H_=512 divisible by 4
  float4 bv = *(const float4*)(bias + n4);
  *(float4*)(att_h + (size_t)idx * 4) = bv;
}

// ---------------------------------------------------------------------------
// Kernel 1: split-K SGEMM: att_h += h[64m,128k] . W[64n,128k]^T per block.
// grid (H/64, B/64, 16 k-slices) = (8,4,16) = 512 blocks, 256 threads.
// LDS tiles stored K-major [BK][64] (stride 68 pads: 16B-aligned rows,
// spreads banks). Micro-tile 4x4 per thread via 2x ds_read_b128 per kk.
// ---------------------------------------------------------------------------
__global__ __launch_bounds__(256) void h2att_kernel(
    const float* __restrict__ h, const float* __restrict__ W,
    float* __restrict__ att_h) {
#define LSTR 68
  __shared__ float a_lds[32][LSTR];
  __shared__ float b_lds[32][LSTR];

  const int tid = threadIdx.x;
  const int n0 = blockIdx.x * 64;
  const int m0 = blockIdx.y * 64;
  const int kslice = blockIdx.z * 128;

  // staging role: row r = tid/4 (0..63), k-chunk = (tid%4)*8  (+0 and +4)
  const int sr = tid >> 2;
  const int sk = (tid & 3) * 8;
  // compute role: 4x4 micro-tile
  const int tm = (tid >> 4) * 4;   // 0,4,..,60
  const int tn = (tid & 15) * 4;   // 0,4,..,60

  float acc[4][4] = {};

  for (int k0 = 0; k0 < 128; k0 += 32) {
    const size_t ka = (size_t)kslice + k0 + sk;
    float4 a0 = *(const float4*)(h + (size_t)(m0 + sr) * D_ + ka);
    float4 a1 = *(const float4*)(h + (size_t)(m0 + sr) * D_ + ka + 4);
    float4 b0 = *(const float4*)(W + (size_t)(n0 + sr) * D_ + ka);
    float4 b1 = *(const float4*)(W + (size_t)(n0 + sr) * D_ + ka + 4);
    __syncthreads();
    a_lds[sk + 0][sr] = a0.x; a_lds[sk + 1][sr] = a0.y;
    a_lds[sk + 2][sr] = a0.z; a_lds[sk + 3][sr] = a0.w;
    a_lds[sk + 4][sr] = a1.x; a_lds[sk + 5][sr] = a1.y;
    a_lds[sk + 6][sr] = a1.z; a_lds[sk + 7][sr] = a1.w;
    b_lds[sk + 0][sr] = b0.x; b_lds[sk + 1][sr] = b0.y;
    b_lds[sk + 2][sr] = b0.z; b_lds[sk + 3][sr] = b0.w;
    b_lds[sk + 4][sr] = b1.x; b_lds[sk + 5][sr] = b1.y;
    b_lds[sk + 6][sr] = b1.z; b_lds[sk + 7][sr] = b1.w;
    __syncthreads();
#pragma unroll
    for (int kk = 0; kk < 32; ++kk) {
      float4 av = *(const float4*)(&a_lds[kk][tm]);
      float4 bv = *(const float4*)(&b_lds[kk][tn]);
      float a[4] = {av.x, av.y, av.z, av.w};
      float b[4] = {bv.x, bv.y, bv.z, bv.w};
#pragma unroll
      for (int i = 0; i < 4; ++i)
#pragma unroll
        for (int j = 0; j < 4; ++j) acc[i][j] = fmaf(a[i], b[j], acc[i][j]);
    }
  }

#pragma unroll
  for (int i = 0; i < 4; ++i)
#pragma unroll
    for (int j = 0; j < 4; ++j)
      atomicAdd(att_h + (size_t)(m0 + tm + i) * H_ + n0 + tn + j, acc[i][j]);
#undef LSTR
}

// ---------------------------------------------------------------------------
// Kernel 2: scores[b,s] = sum_h tanh(p[b,s,h] + att_h[b,h]) * w_alpha[h] + b_a
// One wave per (b,s). Streams 103 MB of p.
// ---------------------------------------------------------------------------
__global__ __launch_bounds__(256) void scores_kernel(
    const float* __restrict__ p, const float* __restrict__ att_h,
    const float* __restrict__ w_alpha, const float* __restrict__ b_alpha,
    float* __restrict__ scores) {
  const int wave = threadIdx.x >> 6;
  const int lane = threadIdx.x & 63;
  const int idx = blockIdx.x * 4 + wave;   // 12544*4 = 50176 = B*S exact
  const int b = idx / S_;

  const float* pp = p + (size_t)idx * H_;
  const float* ah = att_h + (size_t)b * H_;

  float acc = 0.f;
#pragma unroll
  for (int h0 = 0; h0 < H_; h0 += 256) {
    const int o = h0 + lane * 4;
    float4 pv = *(const float4*)(pp + o);
    float4 av = *(const float4*)(ah + o);
    float4 wv = *(const float4*)(w_alpha + o);
    acc += fast_tanh(pv.x + av.x) * wv.x;
    acc += fast_tanh(pv.y + av.y) * wv.y;
    acc += fast_tanh(pv.z + av.z) * wv.z;
    acc += fast_tanh(pv.w + av.w) * wv.w;
  }
#pragma unroll
  for (int off = 32; off > 0; off >>= 1) acc += __shfl_down(acc, off);
  if (lane == 0) scores[idx] = acc + b_alpha[0];
}

// ---------------------------------------------------------------------------
// Kernel 3: weight[b,s] = renorm(softmax(scores[b,:]) * mask[b,:]).
// ---------------------------------------------------------------------------
__global__ __launch_bounds__(256) void softmax_kernel(
    const float* __restrict__ scores, const float* __restrict__ mask,
    float* __restrict__ weight) {
  __shared__ float red[4];
  const int tid = threadIdx.x;
  const int b = blockIdx.x;
  const int wave = tid >> 6, lane = tid & 63;

  float sc = (tid < S_) ? scores[(size_t)b * S_ + tid] : -INFINITY;

  float v = sc;
#pragma unroll
  for (int off = 32; off > 0; off >>= 1) v = fmaxf(v, __shfl_down(v, off));
  if (lane == 0) red[wave] = v;
  __syncthreads();
  float mx = fmaxf(fmaxf(red[0], red[1]), fmaxf(red[2], red[3]));
  __syncthreads();

  float e = (tid < S_) ? __expf(sc - mx) : 0.f;

  v = e;
#pragma unroll
  for (int off = 32; off > 0; off >>= 1) v += __shfl_down(v, off);
  if (lane == 0) red[wave] = v;
  __syncthreads();
  float z = red[0] + red[1] + red[2] + red[3];
  __syncthreads();

  float w = (tid < S_) ? (e / z) * mask[(size_t)b * S_ + tid] : 0.f;

  v = w;
#pragma unroll
  for (int off = 32; off > 0; off >>= 1) v += __shfl_down(v, off);
  if (lane == 0) red[wave] = v;
  __syncthreads();
  float z2 = red[0] + red[1] + red[2] + red[3];

  if (tid < S_) weight[(size_t)b * S_ + tid] = w / z2;
}

// ---------------------------------------------------------------------------
// Kernel 4: out[b,d] = sum_s weight[b,s] * att_feats[b,s,d].
// grid (D/512, B) = 1024 blocks, 128 threads, float4/thread, s-unroll x7.
// ---------------------------------------------------------------------------
__global__ __launch_bounds__(128) void attres_kernel(
    const float* __restrict__ weight, const float* __restrict__ att_feats,
    float* __restrict__ out) {
  __shared__ float w_lds[S_];
  const int tid = threadIdx.x;
  const int b = blockIdx.y;

  if (tid < S_) w_lds[tid] = weight[(size_t)b * S_ + tid];
  if (tid + 128 < S_) w_lds[tid + 128] = weight[(size_t)b * S_ + tid + 128];
  __syncthreads();

  const int d0 = blockIdx.x * 512 + tid * 4;
  const float* base = att_feats + (size_t)b * S_ * D_ + d0;

  float4 acc = {0.f, 0.f, 0.f, 0.f};
#pragma unroll 2
  for (int so = 0; so < S_; so += 7) {      // 196 = 28 * 7
    float4 v0 = *(const float4*)(base + (size_t)(so + 0) * D_);
    float4 v1 = *(const float4*)(base + (size_t)(so + 1) * D_);
    float4 v2 = *(const float4*)(base + (size_t)(so + 2) * D_);
    float4 v3 = *(const float4*)(base + (size_t)(so + 3) * D_);
    float4 v4 = *(const float4*)(base + (size_t)(so + 4) * D_);
    float4 v5 = *(const float4*)(base + (size_t)(so + 5) * D_);
    float4 v6 = *(const float4*)(base + (size_t)(so + 6) * D_);
    float w0 = w_lds[so + 0], w1 = w_lds[so + 1], w2 = w_lds[so + 2];
    float w3 = w_lds[so + 3], w4 = w_lds[so + 4], w5 = w_lds[so + 5];
    float w6 = w_lds[so + 6];
    acc.x = fmaf(w0, v0.x, acc.x); acc.y = fmaf(w0, v0.y, acc.y);
    acc.z = fmaf(w0, v0.z, acc.z); acc.w = fmaf(w0, v0.w, acc.w);
    acc.x = fmaf(w1, v1.x, acc.x); acc.y = fmaf(w1, v1.y, acc.y);
    acc.z = fmaf(w1, v1.z, acc.z); acc.w = fmaf(w1, v1.w, acc.w);
    acc.x = fmaf(w2, v2.x, acc.x); acc.y = fmaf(w2, v2.y, acc.y);
    acc.z = fmaf(w2, v2.z, acc.z); acc.w = fmaf(w2, v2.w, acc.w);
    acc.x = fmaf(w3, v3.x, acc.x); acc.y = fmaf(w3, v3.y, acc.y);
    acc.z = fmaf(w3, v3.z, acc.z); acc.w = fmaf(w3, v3.w, acc.w);
    acc.x = fmaf(w4, v4.x, acc.x); acc.y = fmaf(w4, v4.y, acc.y);
    acc.z = fmaf(w4, v4.z, acc.z); acc.w = fmaf(w4, v4.w, acc.w);
    acc.x = fmaf(w5, v5.x, acc.x); acc.y = fmaf(w5, v5.y, acc.y);
    acc.z = fmaf(w5, v5.z, acc.z); acc.w = fmaf(w5, v5.w, acc.w);
    acc.x = fmaf(w6, v6.x, acc.x); acc.y = fmaf(w6, v6.y, acc.y);
    acc.z = fmaf(w6, v6.z, acc.z); acc.w = fmaf(w6, v6.w, acc.w);
  }
  *(float4*)(out + (size_t)b * D_ + d0) = acc;
}

// ---------------------------------------------------------------------------
extern "C" void kernel_launch(void* const* d_in, const int* in_sizes, int n_in,
                              void* d_out, int out_size, void* d_ws, size_t ws_size,
                              hipStream_t stream) {
  const float* h         = (const float*)d_in[0];   // [B,D]
  const float* att_feats = (const float*)d_in[1];   // [B,S,D]
  const float* p_att     = (const float*)d_in[2];   // [B,S,H]
  const float* att_masks = (const float*)d_in[3];   // [B,S]
  const float* W_h2att   = (const float*)d_in[4];   // [H,D]
  const float* b_h2att   = (const float*)d_in[5];   // [H]
  const float* w_alpha   = (const float*)d_in[6];   // [H]
  const float* b_alpha   = (const float*)d_in[7];   // [1]
  float* out = (float*)d_out;                       // [B,D]

  float* att_h  = (float*)d_ws;                     // B*H = 131072 floats
  float* scores = att_h + (size_t)B_ * H_;          // B*S = 50176 floats
  float* weight = scores + (size_t)B_ * S_;         // B*S = 50176 floats

  // K0: att_h = bias (init for split-K atomics)
  bias_init_kernel<<<128, 256, 0, stream>>>(b_h2att, att_h);

  // K1: att_h += h . W^T  (split-K x16, 512 blocks)
  dim3 g1(H_ / 64, B_ / 64, 16);
  h2att_kernel<<<g1, 256, 0, stream>>>(h, W_h2att, att_h);

  // K2: scores (12544 blocks, streams p_att 103 MB)
  scores_kernel<<<(B_ * S_) / 4, 256, 0, stream>>>(p_att, att_h, w_alpha,
                                                   b_alpha, scores);

  // K3: softmax -> weight (256 blocks, tiny)
  softmax_kernel<<<B_, 256, 0, stream>>>(scores, att_masks, weight);

  // K4: weighted sum (1024 blocks, streams att_feats 411 MB)
  dim3 g4(D_ / 512, B_);
  attres_kernel<<<g4, 128, 0, stream>>>(weight, att_feats, out);
}